// Round 6
// baseline (44411.774 us; speedup 1.0000x reference)
//
#include <hip/hip_runtime.h>
#include <math.h>

typedef unsigned short u16;
typedef unsigned int u32;

#define FEATN 66
#define HIDN 256
#define NNDIM 16896      // 66*256
#define INVS 0.9999950000374998f
#ifndef M_PI
#define M_PI 3.14159265358979323846
#endif

// ---- dct (fp32, from double math, as numpy does) + true inverse via Gauss-Jordan ----
__global__ void build_mats(float* __restrict__ dct, float* __restrict__ idct) {
    if (threadIdx.x != 0 || blockIdx.x != 0) return;
    for (int k = 0; k < 20; k++) {
        double w = (k == 0) ? sqrt(1.0 / 20.0) : sqrt(2.0 / 20.0);
        for (int i = 0; i < 20; i++)
            dct[k * 20 + i] = (float)(w * cos(M_PI * (i + 0.5) * k / 20.0));
    }
    double A[20][40];
    for (int r = 0; r < 20; r++)
        for (int c = 0; c < 20; c++) {
            A[r][c] = (double)dct[r * 20 + c];
            A[r][20 + c] = (r == c) ? 1.0 : 0.0;
        }
    for (int col = 0; col < 20; col++) {
        int piv = col; double best = fabs(A[col][col]);
        for (int r = col + 1; r < 20; r++) {
            double a = fabs(A[r][col]);
            if (a > best) { best = a; piv = r; }
        }
        if (piv != col)
            for (int c = 0; c < 40; c++) { double t = A[col][c]; A[col][c] = A[piv][c]; A[piv][c] = t; }
        double p = A[col][col];
        for (int c = 0; c < 40; c++) A[col][c] /= p;
        for (int r = 0; r < 20; r++) {
            if (r == col) continue;
            double m = A[r][col];
            if (m != 0.0) for (int c = 0; c < 40; c++) A[r][c] -= m * A[col][c];
        }
    }
    for (int r = 0; r < 20; r++)
        for (int c = 0; c < 20; c++) idct[r * 20 + c] = (float)A[r][20 + c];
}

// ---- conv layer 1 (in-ch 66, kernel 6): out[b,c,p] = relu(sum_{f,t} x[b,off+p+t,f]*w[c,f,t] + b[c])
__global__ __launch_bounds__(256) void conv1_kernel(
    const float* __restrict__ x, const float* __restrict__ w,
    const float* __restrict__ bias, float* __restrict__ out,
    int C, int P, int off) {
    int gid = blockIdx.x * 256 + threadIdx.x;
    int total = C * 256 * P;
    if (gid >= total) return;
    int b = gid / (256 * P), rem = gid % (256 * P), c = rem / P, p = rem % P;
    float acc = bias[c];
    const float* xb = x + (size_t)b * 3300 + (size_t)(off + p) * 66;
    const float* wc = w + (size_t)c * 396;
    for (int t = 0; t < 6; t++)
        for (int f = 0; f < 66; f++)
            acc = fmaf(xb[t * 66 + f], wc[f * 6 + t], acc);
    out[(size_t)b * (256 * P) + c * P + p] = fmaxf(acc, 0.f);
}

// ---- conv layer 2 (in-ch 256, kernel 5): in width P+4 -> out width P
__global__ __launch_bounds__(256) void conv2_kernel(
    const float* __restrict__ in, const float* __restrict__ w,
    const float* __restrict__ bias, float* __restrict__ out,
    int C, int P) {
    int gid = blockIdx.x * 256 + threadIdx.x;
    int total = C * 256 * P;
    if (gid >= total) return;
    int b = gid / (256 * P), rem = gid % (256 * P), c = rem / P, s = rem % P;
    float acc = bias[c];
    const float* ib = in + (size_t)b * 256 * (P + 4);
    const float* wc = w + (size_t)c * 1280;
    for (int h = 0; h < 256; h++)
        for (int t = 0; t < 5; t++)
            acc = fmaf(ib[h * (P + 4) + s + t], wc[h * 5 + t], acc);
    out[(size_t)b * (256 * P) + c * P + s] = fmaxf(acc, 0.f);
}

// ---- attention weights: one thread per batch ----
__global__ void att_simple(const float* __restrict__ q2, const float* __restrict__ k2,
                           float* __restrict__ att, int C) {
    int b = blockIdx.x * 64 + threadIdx.x;
    if (b >= C) return;
    const float* q = q2 + (size_t)b * 256;
    const float* k = k2 + (size_t)b * 7936;
    float sc[31];
    for (int s = 0; s < 31; s++) sc[s] = 0.f;
    for (int c = 0; c < 256; c++) {
        float qv = q[c];
        for (int s = 0; s < 31; s++) sc[s] = fmaf(qv, k[c * 31 + s], sc[s]);
    }
    float tot = 0.f;
    for (int s = 0; s < 31; s++) tot += sc[s];
    float inv = (tot != 0.f) ? (1.f / tot) : 0.f;
    for (int s = 0; s < 31; s++) att[(size_t)b * 32 + s] = sc[s] * inv;
}

// ---- gcn_inp = concat(padded_query, att_final) ----
__global__ __launch_bounds__(256) void gcn_inp_naive(
    const float* __restrict__ x, const float* __restrict__ att,
    const float* __restrict__ dct, float* __restrict__ gi, int C) {
    int gid = blockIdx.x * 256 + threadIdx.x;
    int total = C * 2640;
    if (gid >= total) return;
    int b = gid / 2640, idx = gid % 2640, n = idx / 40, l = idx % 40;
    const float* xb = x + (size_t)b * 3300;
    float acc = 0.f;
    if (l < 20) {
        for (int l1 = 0; l1 < 20; l1++) {
            int r = (l1 < 10) ? (40 + l1) : 49;   // pidx
            acc = fmaf(xb[r * 66 + n], dct[l1 * 20 + l], acc);
        }
    } else {
        int j = l - 20;
        for (int s2 = 0; s2 < 31; s2++) {
            int m = n * 31 + s2;                   // flat-reshape semantics
            int s1 = m / 66, f1 = m - s1 * 66;
            float inner = 0.f;
            for (int l1 = 0; l1 < 20; l1++)
                inner = fmaf(xb[(s1 + l1) * 66 + f1], dct[l1 * 20 + j], inner);
            acc = fmaf(att[(size_t)b * 32 + s2], inner, acc);
        }
    }
    gi[(size_t)b * 2640 + idx] = acc;
}

// ---- attmul: out[b,n,f] = sum_m A[n,m] * S[b,m,f]   (width W) ----
__global__ __launch_bounds__(256) void attmul_naive(
    const float* __restrict__ S, const float* __restrict__ A,
    float* __restrict__ out, int C, int W) {
    int per = 66 * W;
    int gid = blockIdx.x * 256 + threadIdx.x;
    int total = C * per;
    if (gid >= total) return;
    int b = gid / per, idx = gid % per, n = idx / W, f = idx % W;
    const float* Sb = S + (size_t)b * per;
    float acc = 0.f;
    for (int m = 0; m < 66; m++)
        acc = fmaf(A[n * 66 + m], Sb[m * W + f], acc);
    out[(size_t)b * per + idx] = acc;
}

// ---- wmul: out = tanh(bn(Z@W + bias)) [+ res] ----
template <int K>
__global__ __launch_bounds__(256) void wmul_naive(
    const float* __restrict__ Z, const float* __restrict__ W,
    const float* __restrict__ bias, const float* __restrict__ g,
    const float* __restrict__ beta, const float* __restrict__ res,
    float* __restrict__ out, int total) {
    int gid = blockIdx.x * 256 + threadIdx.x;
    if (gid >= total) return;
    int r = gid >> 8, f = gid & 255, n = r % 66;
    const float* zr = Z + (size_t)r * K;
    float acc = 0.f;
    for (int i = 0; i < K; i++)
        acc = fmaf(zr[i], W[(size_t)i * 256 + f], acc);
    float v = (acc + bias[f]) * INVS;
    v = tanhf(fmaf(v, g[n * 256 + f], beta[n * 256 + f]));
    if (res) v += res[gid];
    out[gid] = v;
}

// ---- final1: go[b,n,l] = gb[l] + gi[b,n,l] + sum_i T[b,n,i]*gw[i,l]  (l<20) ----
__global__ __launch_bounds__(256) void final1_naive(
    const float* __restrict__ T, const float* __restrict__ gw,
    const float* __restrict__ gb, const float* __restrict__ gi,
    float* __restrict__ go, int C) {
    int gid = blockIdx.x * 256 + threadIdx.x;
    int total = C * 1320;
    if (gid >= total) return;
    int b = gid / 1320, idx = gid % 1320, n = idx / 20, l = idx % 20;
    float acc = gb[l] + gi[(size_t)b * 2640 + n * 40 + l];
    const float* tb = T + (size_t)b * NNDIM + n * 256;
    for (int i = 0; i < 256; i++)
        acc = fmaf(tb[i], gw[i * 40 + l], acc);
    go[gid] = acc;
}

// ---- final2: out[b,n,m] = sum_l go[b,n,l] * idct[l,m]  (f32 store) ----
__global__ __launch_bounds__(256) void final2_naive(
    const float* __restrict__ go, const float* __restrict__ idct,
    float* __restrict__ out, int C) {
    int gid = blockIdx.x * 256 + threadIdx.x;
    int total = C * 1320;
    if (gid >= total) return;
    int idx = gid % 1320, n = idx / 20, m = idx % 20;
    const float* gr = go + (size_t)(gid / 1320) * 1320 + n * 20;
    float acc = 0.f;
    for (int l = 0; l < 20; l++)
        acc = fmaf(gr[l], idct[l * 20 + m], acc);
    out[gid] = acc;
}

static inline int grid_for(int total) { return (total + 255) / 256; }

extern "C" void kernel_launch(void* const* d_in, const int* in_sizes, int n_in,
                              void* d_out, int out_size, void* d_ws, size_t ws_size,
                              hipStream_t stream) {
    const float* x        = (const float*)d_in[0];
    const float* q_w1     = (const float*)d_in[1];
    const float* q_b1     = (const float*)d_in[2];
    const float* q_w2     = (const float*)d_in[3];
    const float* q_b2     = (const float*)d_in[4];
    const float* k_w1     = (const float*)d_in[5];
    const float* k_b1     = (const float*)d_in[6];
    const float* k_w2     = (const float*)d_in[7];
    const float* k_b2     = (const float*)d_in[8];
    const float* gin_w    = (const float*)d_in[9];
    const float* gin_att  = (const float*)d_in[10];
    const float* gin_b    = (const float*)d_in[11];
    const float* bn_in_g  = (const float*)d_in[12];
    const float* bn_in_b  = (const float*)d_in[13];
    const float* blk_w    = (const float*)d_in[14];
    const float* blk_att  = (const float*)d_in[15];
    const float* blk_b    = (const float*)d_in[16];
    const float* blk_bn_g = (const float*)d_in[17];
    const float* blk_bn_b = (const float*)d_in[18];
    const float* gout_w   = (const float*)d_in[19];
    const float* gout_att = (const float*)d_in[20];
    const float* gout_b   = (const float*)d_in[21];
    float* out = (float*)d_out;   // output dtype: f32 (matches reference)

    const int B = in_sizes[0] / 3300;

    // Dedicated (non-aliased) per-batch float counts:
    // q1 1280 | q2 256 | k1 8960 | k2 7936 | att 32 | gi 2640 | Y 16896 | Z 16896 | T 16896 | go 1320
    const size_t PER_B = 73112ull * 4ull;   // 292,448 bytes/batch
    float* dctb  = (float*)d_ws;            // 400 floats
    float* idctb = dctb + 400;              // 400 floats
    char* R = (char*)d_ws + 8192;
    size_t avail = (ws_size > 8192) ? (ws_size - 8192) : 0;
    int C = B;
    while (C > 1 && (size_t)C * PER_B > avail) C >>= 1;

    build_mats<<<1, 64, 0, stream>>>(dctb, idctb);

    for (int c0 = 0; c0 < B; c0 += C) {
        const int Cc = (B - c0 < C) ? (B - c0) : C;
        const float* xc = x + (size_t)c0 * 3300;
        float* outc = out + (size_t)c0 * 1320;

        float* q1b = (float*)R;
        float* q2b = q1b + (size_t)C * 1280;
        float* k1b = q2b + (size_t)C * 256;
        float* k2b = k1b + (size_t)C * 8960;
        float* ab  = k2b + (size_t)C * 7936;
        float* gib = ab  + (size_t)C * 32;
        float* Yb  = gib + (size_t)C * 2640;
        float* Zb  = Yb  + (size_t)C * 16896;
        float* Tb  = Zb  + (size_t)C * 16896;
        float* gob = Tb  + (size_t)C * 16896;

        conv1_kernel<<<grid_for(Cc * 1280), 256, 0, stream>>>(xc, q_w1, q_b1, q1b, Cc, 5, 40);
        conv1_kernel<<<grid_for(Cc * 8960), 256, 0, stream>>>(xc, k_w1, k_b1, k1b, Cc, 35, 0);
        conv2_kernel<<<grid_for(Cc * 256), 256, 0, stream>>>(q1b, q_w2, q_b2, q2b, Cc, 1);
        conv2_kernel<<<grid_for(Cc * 7936), 256, 0, stream>>>(k1b, k_w2, k_b2, k2b, Cc, 31);
        att_simple<<<(Cc + 63) / 64, 64, 0, stream>>>(q2b, k2b, ab, Cc);
        gcn_inp_naive<<<grid_for(Cc * 2640), 256, 0, stream>>>(xc, ab, dctb, gib, Cc);

        const int tot = Cc * NNDIM;
        // gin: Z0 = gin_att @ gcn_inp (into Tb, 40-wide); Y = tanh(bn(Z0 @ gin_w + gin_b))
        attmul_naive<<<grid_for(Cc * 2640), 256, 0, stream>>>(gib, gin_att, Tb, Cc, 40);
        wmul_naive<40><<<grid_for(tot), 256, 0, stream>>>(Tb, gin_w, gin_b,
                                                          bn_in_g, bn_in_b, nullptr, Yb, tot);
        float* ycur = Yb;
        float* yscr = Zb;
        for (int i = 0; i < 12; i += 2) {
            attmul_naive<<<grid_for(tot), 256, 0, stream>>>(ycur, blk_att + (size_t)i * 4356, Tb, Cc, 256);
            wmul_naive<256><<<grid_for(tot), 256, 0, stream>>>(
                Tb, blk_w + (size_t)i * 65536, blk_b + (size_t)i * 256,
                blk_bn_g + (size_t)i * NNDIM, blk_bn_b + (size_t)i * NNDIM,
                nullptr, yscr, tot);
            attmul_naive<<<grid_for(tot), 256, 0, stream>>>(yscr, blk_att + (size_t)(i + 1) * 4356, Tb, Cc, 256);
            wmul_naive<256><<<grid_for(tot), 256, 0, stream>>>(
                Tb, blk_w + (size_t)(i + 1) * 65536, blk_b + (size_t)(i + 1) * 256,
                blk_bn_g + (size_t)(i + 1) * NNDIM, blk_bn_b + (size_t)(i + 1) * NNDIM,
                ycur /* residual */, yscr, tot);
            float* t = ycur; ycur = yscr; yscr = t;
        }
        // gout + idct
        attmul_naive<<<grid_for(tot), 256, 0, stream>>>(ycur, gout_att, Tb, Cc, 256);
        final1_naive<<<grid_for(Cc * 1320), 256, 0, stream>>>(Tb, gout_w, gout_b, gib, gob, Cc);
        final2_naive<<<grid_for(Cc * 1320), 256, 0, stream>>>(gob, idctb, outc, Cc);
    }
}

// Round 7
// 10597.092 us; speedup vs baseline: 4.1909x; 4.1909x over previous
//
#include <hip/hip_runtime.h>
#include <math.h>

typedef unsigned short u16;
typedef unsigned int u32;

#define FEATN 66
#define HIDN 256
#define NNDIM 16896      // 66*256
#define INVS 0.9999950000374998f
#ifndef M_PI
#define M_PI 3.14159265358979323846
#endif

// ---------------- DCT matrix (parallel build; orthonormal: inv = transpose) ----------------
__global__ void dct_kernel(float* __restrict__ dct) {
    int t = threadIdx.x;
    if (t < 400) {
        int k = t / 20, i = t % 20;
        double w = (k == 0) ? sqrt(1.0 / 20.0) : sqrt(2.0 / 20.0);
        dct[t] = (float)(w * cos(M_PI * (i + 0.5) * k / 20.0));
    }
}

// ---------------- conv q1: x[b,40:50,:] -> q1[b,c,p] p<5 ----------------
__global__ __launch_bounds__(256) void conv_q1_kernel(
    const float* __restrict__ x, const float* __restrict__ w1,
    const float* __restrict__ b1, float* __restrict__ q1) {
    __shared__ float xs[10 * FEATN];
    const int b = blockIdx.x, tid = threadIdx.x;
    const float* xb = x + (size_t)b * 3300 + 40 * FEATN;
    for (int idx = tid; idx < 660; idx += 256) xs[idx] = xb[idx];
    __syncthreads();
    const int c = tid;
    float acc[5];
    float bv = b1[c];
#pragma unroll
    for (int p = 0; p < 5; p++) acc[p] = bv;
    const float* wc = w1 + (size_t)c * 396;
    for (int f = 0; f < FEATN; f++) {
        float xr[10];
#pragma unroll
        for (int j = 0; j < 10; j++) xr[j] = xs[j * FEATN + f];
#pragma unroll
        for (int t = 0; t < 6; t++) {
            float wv = wc[f * 6 + t];
#pragma unroll
            for (int p = 0; p < 5; p++) acc[p] = fmaf(xr[p + t], wv, acc[p]);
        }
    }
#pragma unroll
    for (int p = 0; p < 5; p++)
        q1[(size_t)b * 1280 + c * 5 + p] = fmaxf(acc[p], 0.f);
}

// ---------------- conv k1: x[b,0:40,:] -> k1[b,c,p] p<35 ----------------
__global__ __launch_bounds__(256) void conv_k1_kernel(
    const float* __restrict__ x, const float* __restrict__ w1,
    const float* __restrict__ b1, float* __restrict__ k1) {
    __shared__ float xs[40 * FEATN];          // 10.56 KB
    const int b = blockIdx.x, ct = blockIdx.y, tid = threadIdx.x;
    const float* xb = x + (size_t)b * 3300;
    for (int idx = tid; idx < 2640; idx += 256) xs[idx] = xb[idx];
    __syncthreads();
    const int c = tid & 31, pg = tid >> 5;    // pg 0..7, only pg<7 active
    if (pg >= 7) return;
    const int cg = ct * 32 + c;
    float acc[5];
    float bv = b1[cg];
#pragma unroll
    for (int q = 0; q < 5; q++) acc[q] = bv;
    const float* wc = w1 + (size_t)cg * 396;
    for (int f = 0; f < FEATN; f++) {
        float xr[10];
#pragma unroll
        for (int j = 0; j < 10; j++) xr[j] = xs[(pg * 5 + j) * FEATN + f];
#pragma unroll
        for (int t = 0; t < 6; t++) {
            float wv = wc[f * 6 + t];
#pragma unroll
            for (int q = 0; q < 5; q++) acc[q] = fmaf(xr[q + t], wv, acc[q]);
        }
    }
#pragma unroll
    for (int q = 0; q < 5; q++)
        k1[(size_t)b * 8960 + cg * 35 + pg * 5 + q] = fmaxf(acc[q], 0.f);
}

// ---------------- conv q2: q1[b,:,0:5] -> q2[b,c], 8 batches/block ----------------
__global__ __launch_bounds__(256) void conv_q2_kernel(
    const float* __restrict__ q1, const float* __restrict__ w2,
    const float* __restrict__ b2, float* __restrict__ q2, int Cc) {
    __shared__ float q1s[8 * 1280];           // 40 KB
    const int b0 = blockIdx.x * 8, tid = threadIdx.x;
    for (int idx = tid; idx < 8 * 1280; idx += 256) {
        int bb = b0 + idx / 1280;
        q1s[idx] = (bb < Cc) ? q1[(size_t)b0 * 1280 + idx] : 0.f;
    }
    __syncthreads();
    const int c = tid;
    float acc[8];
    float bv = b2[c];
#pragma unroll
    for (int bb = 0; bb < 8; bb++) acc[bb] = bv;
    const float* wc = w2 + (size_t)c * 1280;
    for (int h = 0; h < 256; h++) {
        float wv[5];
#pragma unroll
        for (int t = 0; t < 5; t++) wv[t] = wc[h * 5 + t];
#pragma unroll
        for (int bb = 0; bb < 8; bb++) {
#pragma unroll
            for (int t = 0; t < 5; t++)
                acc[bb] = fmaf(q1s[bb * 1280 + h * 5 + t], wv[t], acc[bb]);
        }
    }
#pragma unroll
    for (int bb = 0; bb < 8; bb++)
        if (b0 + bb < Cc)
            q2[(size_t)(b0 + bb) * 256 + c] = fmaxf(acc[bb], 0.f);
}

// ---------------- conv k2: k1[b,:,s:s+5] -> k2[b,c,s] s<31 ----------------
__global__ __launch_bounds__(256) void conv_k2_kernel(
    const float* __restrict__ k1, const float* __restrict__ w2,
    const float* __restrict__ b2, float* __restrict__ k2) {
    __shared__ float k1s[256 * 35];           // 35.8 KB
    const int b = blockIdx.x, tid = threadIdx.x;
    for (int idx = tid; idx < 8960; idx += 256)
        k1s[idx] = k1[(size_t)b * 8960 + idx];
    __syncthreads();
    const int c = tid;
    float acc[31];
    float bv = b2[c];
#pragma unroll
    for (int s = 0; s < 31; s++) acc[s] = bv;
    const float* wc = w2 + (size_t)c * 1280;
    for (int h = 0; h < 256; h++) {
        float row[35];
#pragma unroll
        for (int j = 0; j < 35; j++) row[j] = k1s[h * 35 + j];
        float wv[5];
#pragma unroll
        for (int t = 0; t < 5; t++) wv[t] = wc[h * 5 + t];
#pragma unroll
        for (int t = 0; t < 5; t++) {
#pragma unroll
            for (int s = 0; s < 31; s++)
                acc[s] = fmaf(row[s + t], wv[t], acc[s]);
        }
    }
#pragma unroll
    for (int s = 0; s < 31; s++)
        k2[(size_t)b * 7936 + c * 31 + s] = fmaxf(acc[s], 0.f);
}

// ---------------- attention weights (one wave per batch) ----------------
__global__ void att_kernel(const float* __restrict__ q2, const float* __restrict__ k2,
                           float* __restrict__ att) {
    __shared__ float q2s[256];
    const int b = blockIdx.x, tid = threadIdx.x;
    for (int i = tid; i < 256; i += 64) q2s[i] = q2[(size_t)b * 256 + i];
    __syncthreads();
    float sc = 0.f;
    if (tid < 31) {
        const float* kp = k2 + (size_t)b * 7936 + tid;
        for (int c = 0; c < 256; c++) sc = fmaf(q2s[c], kp[c * 31], sc);
    }
    float tot = sc;
#pragma unroll
    for (int off = 1; off < 64; off <<= 1) tot += __shfl_xor(tot, off);
    if (tid < 31) att[(size_t)b * 32 + tid] = (tot != 0.f) ? (sc / tot) : 0.f;
}

// ---------------- gcn_inp = concat(padded_query, att_final) ----------------
__global__ __launch_bounds__(256) void gcn_inp_kernel(
    const float* __restrict__ x, const float* __restrict__ att,
    const float* __restrict__ dct, float* __restrict__ ginp) {
    __shared__ float xs[3300];
    __shared__ float dctS[400];
    __shared__ float attS[31];
    const int b = blockIdx.x, tid = threadIdx.x;
    const float* xb = x + (size_t)b * 3300;
    for (int idx = tid; idx < 3300; idx += 256) xs[idx] = xb[idx];
    for (int idx = tid; idx < 400; idx += 256) dctS[idx] = dct[idx];
    if (tid < 31) attS[tid] = att[(size_t)b * 32 + tid];
    __syncthreads();
    for (int idx = tid; idx < 2640; idx += 256) {
        int n = idx / 40, l = idx - n * 40;
        float acc = 0.f;
        if (l < 20) {
#pragma unroll
            for (int l1 = 0; l1 < 20; l1++) {
                int r = (l1 < 10) ? (40 + l1) : 49;   // pidx
                acc = fmaf(xs[r * FEATN + n], dctS[l1 * 20 + l], acc);
            }
        } else {
            int j = l - 20;
            for (int s2 = 0; s2 < 31; s2++) {
                int m = n * 31 + s2;                   // flat-reshape semantics
                int s1 = m / 66, f1 = m - s1 * 66;
                float inner = 0.f;
#pragma unroll
                for (int l1 = 0; l1 < 20; l1++)
                    inner = fmaf(xs[(s1 + l1) * FEATN + f1], dctS[l1 * 20 + j], inner);
                acc = fmaf(attS[s2], inner, acc);
            }
        }
        ginp[(size_t)b * 2640 + idx] = acc;
    }
}

// ---------------- attmul (gin, 40-wide): T[b] = gin_att @ gi[b] ----------------
__global__ __launch_bounds__(256) void attmul_gin_kernel(
    const float* __restrict__ ginp, const float* __restrict__ attm,
    float* __restrict__ out) {
    __shared__ float gS[2640];
    __shared__ float attS[4356];
    const int b = blockIdx.x, tid = threadIdx.x;
    for (int idx = tid; idx < 2640; idx += 256) gS[idx] = ginp[(size_t)b * 2640 + idx];
    for (int idx = tid; idx < 4356; idx += 256) attS[idx] = attm[idx];
    __syncthreads();
    for (int idx = tid; idx < 2640; idx += 256) {
        int n = idx / 40, l = idx - n * 40;
        float acc = 0.f;
        for (int m = 0; m < 66; m++)
            acc = fmaf(attS[n * 66 + m], gS[m * 40 + l], acc);
        out[(size_t)b * 2640 + idx] = acc;
    }
}

// ---------------- attmul (256-wide): out[b] = attm @ S[b], column-tiled ----------------
__global__ __launch_bounds__(256) void attmul_kernel(
    const float* __restrict__ S, const float* __restrict__ attm,
    float* __restrict__ out) {
    __shared__ float Ss[66 * 64];             // 16.9 KB
    __shared__ float attS[4356];              // 17.4 KB
    const int b = blockIdx.x, tid = threadIdx.x;
    for (int idx = tid; idx < 4356; idx += 256) attS[idx] = attm[idx];
    const float* Sb = S + (size_t)b * NNDIM;
    float* ob = out + (size_t)b * NNDIM;
    const int fl = tid & 63, ng = tid >> 6;
    for (int f0 = 0; f0 < 256; f0 += 64) {
        __syncthreads();
        for (int idx = tid; idx < 66 * 64; idx += 256) {
            int m = idx >> 6, j = idx & 63;
            Ss[idx] = Sb[m * 256 + f0 + j];
        }
        __syncthreads();
        for (int n = ng; n < 66; n += 4) {
            float acc = 0.f;
            const float* ar = &attS[n * 66];
#pragma unroll 11
            for (int m = 0; m < 66; m++)
                acc = fmaf(ar[m], Ss[(m << 6) + fl], acc);
            ob[n * 256 + f0 + fl] = acc;
        }
    }
}

// ---------------- wmul: out = tanh(bn(Z@W + bias)) [+ res]; 32 rows/block ----------------
template <int K, bool RES>
__global__ __launch_bounds__(256) void wmul_kernel(
    const float* __restrict__ Z, const float* __restrict__ W,
    const float* __restrict__ bias, const float* __restrict__ g,
    const float* __restrict__ beta, const float* __restrict__ res,
    float* __restrict__ out, int rows) {
    __shared__ float As[32 * K];              // 32 KB for K=256
    const int tid = threadIdx.x;
    const size_t row0 = (size_t)blockIdx.x * 32;
    for (int idx = tid; idx < 32 * K; idx += 256) {
        int r = (int)row0 + idx / K;
        As[idx] = (r < rows) ? Z[row0 * K + idx] : 0.f;
    }
    __syncthreads();
    const int fq = tid & 63, rg = tid >> 6;
    float acc[8][4];
#pragma unroll
    for (int r = 0; r < 8; r++)
#pragma unroll
        for (int c = 0; c < 4; c++) acc[r][c] = 0.f;
    for (int i = 0; i < K; i += 4) {
        float w0[4], w1[4], w2[4], w3[4];
#pragma unroll
        for (int fi = 0; fi < 4; fi++) {
            w0[fi] = W[(size_t)(i + 0) * HIDN + fi * 64 + fq];
            w1[fi] = W[(size_t)(i + 1) * HIDN + fi * 64 + fq];
            w2[fi] = W[(size_t)(i + 2) * HIDN + fi * 64 + fq];
            w3[fi] = W[(size_t)(i + 3) * HIDN + fi * 64 + fq];
        }
#pragma unroll
        for (int rr = 0; rr < 8; rr++) {
            const float4 a = *(const float4*)&As[(rg * 8 + rr) * K + i];
#pragma unroll
            for (int fi = 0; fi < 4; fi++) {
                acc[rr][fi] = fmaf(a.x, w0[fi], acc[rr][fi]);
                acc[rr][fi] = fmaf(a.y, w1[fi], acc[rr][fi]);
                acc[rr][fi] = fmaf(a.z, w2[fi], acc[rr][fi]);
                acc[rr][fi] = fmaf(a.w, w3[fi], acc[rr][fi]);
            }
        }
    }
#pragma unroll
    for (int rr = 0; rr < 8; rr++) {
        int r = (int)row0 + rg * 8 + rr;
        if (r >= rows) continue;
        int n = r % 66;
#pragma unroll
        for (int fi = 0; fi < 4; fi++) {
            int f = fi * 64 + fq;
            float v = (acc[rr][fi] + bias[f]) * INVS;
            v = tanhf(fmaf(v, g[n * 256 + f], beta[n * 256 + f]));
            if (RES) v += res[(size_t)r * 256 + f];
            out[(size_t)r * 256 + f] = v;
        }
    }
}

// ---------------- final: go = (T@gw)[:, :20] + gb + gi[:, :20]; out = go @ dct^T ----------------
__global__ __launch_bounds__(256) void final_kernel(
    const float* __restrict__ T, const float* __restrict__ gw,
    const float* __restrict__ gb, const float* __restrict__ gi,
    const float* __restrict__ dct, float* __restrict__ out) {
    __shared__ float Zt[66 * 64];             // 16.9 KB
    __shared__ float gwS[256 * 20];           // 20.5 KB
    __shared__ float goS[1320];               // 5.3 KB
    __shared__ float dctS[400];               // 1.6 KB
    const int b = blockIdx.x, tid = threadIdx.x;
    for (int idx = tid; idx < 5120; idx += 256) {
        int i = idx / 20, l = idx - i * 20;
        gwS[idx] = gw[i * 40 + l];
    }
    for (int idx = tid; idx < 400; idx += 256) dctS[idx] = dct[idx];
    for (int idx = tid; idx < 1320; idx += 256) {
        int n = idx / 20, l = idx - n * 20;
        goS[idx] = gb[l] + gi[(size_t)b * 2640 + n * 40 + l];
    }
    for (int t = 0; t < 4; t++) {
        __syncthreads();
        for (int idx = tid; idx < 66 * 64; idx += 256) {
            int m = idx >> 6, j = idx & 63;
            Zt[idx] = T[(size_t)b * NNDIM + m * 256 + t * 64 + j];
        }
        __syncthreads();
        for (int idx = tid; idx < 1320; idx += 256) {
            int n = idx / 20, l = idx - n * 20;
            float acc = 0.f;
#pragma unroll
            for (int j = 0; j < 64; j++)
                acc = fmaf(Zt[(n << 6) + j], gwS[(t * 64 + j) * 20 + l], acc);
            goS[idx] += acc;
        }
    }
    __syncthreads();
    for (int idx = tid; idx < 1320; idx += 256) {
        int n = idx / 20, mm = idx - n * 20;
        float o = 0.f;
#pragma unroll
        for (int l = 0; l < 20; l++)
            o = fmaf(goS[n * 20 + l], dctS[mm * 20 + l], o);   // idct = dct^T
        out[(size_t)b * 1320 + idx] = o;
    }
}

extern "C" void kernel_launch(void* const* d_in, const int* in_sizes, int n_in,
                              void* d_out, int out_size, void* d_ws, size_t ws_size,
                              hipStream_t stream) {
    const float* x        = (const float*)d_in[0];
    const float* q_w1     = (const float*)d_in[1];
    const float* q_b1     = (const float*)d_in[2];
    const float* q_w2     = (const float*)d_in[3];
    const float* q_b2     = (const float*)d_in[4];
    const float* k_w1     = (const float*)d_in[5];
    const float* k_b1     = (const float*)d_in[6];
    const float* k_w2     = (const float*)d_in[7];
    const float* k_b2     = (const float*)d_in[8];
    const float* gin_w    = (const float*)d_in[9];
    const float* gin_att  = (const float*)d_in[10];
    const float* gin_b    = (const float*)d_in[11];
    const float* bn_in_g  = (const float*)d_in[12];
    const float* bn_in_b  = (const float*)d_in[13];
    const float* blk_w    = (const float*)d_in[14];
    const float* blk_att  = (const float*)d_in[15];
    const float* blk_b    = (const float*)d_in[16];
    const float* blk_bn_g = (const float*)d_in[17];
    const float* blk_bn_b = (const float*)d_in[18];
    const float* gout_w   = (const float*)d_in[19];
    const float* gout_att = (const float*)d_in[20];
    const float* gout_b   = (const float*)d_in[21];
    float* out = (float*)d_out;   // output dtype: f32

    const int B = in_sizes[0] / 3300;

    // Non-aliased per-batch float counts:
    // q1 1280 | q2 256 | k1 8960 | k2 7936 | att 32 | gi 2640 | Y 16896 | Z 16896 | T 16896
    const size_t PER_B = 71792ull * 4ull;   // 287,168 bytes/batch
    float* dctb = (float*)d_ws;             // 400 floats
    char* R = (char*)d_ws + 8192;
    size_t avail = (ws_size > 8192) ? (ws_size - 8192) : 0;
    int C = B;
    while (C > 1 && (size_t)C * PER_B > avail) C >>= 1;

    dct_kernel<<<1, 512, 0, stream>>>(dctb);

    for (int c0 = 0; c0 < B; c0 += C) {
        const int Cc = (B - c0 < C) ? (B - c0) : C;
        const float* xc = x + (size_t)c0 * 3300;
        float* outc = out + (size_t)c0 * 1320;

        float* q1b = (float*)R;
        float* q2b = q1b + (size_t)C * 1280;
        float* k1b = q2b + (size_t)C * 256;
        float* k2b = k1b + (size_t)C * 8960;
        float* ab  = k2b + (size_t)C * 7936;
        float* gib = ab  + (size_t)C * 32;
        float* Yb  = gib + (size_t)C * 2640;
        float* Zb  = Yb  + (size_t)C * 16896;
        float* Tb  = Zb  + (size_t)C * 16896;

        conv_q1_kernel<<<Cc, 256, 0, stream>>>(xc, q_w1, q_b1, q1b);
        conv_k1_kernel<<<dim3(Cc, 8), 256, 0, stream>>>(xc, k_w1, k_b1, k1b);
        conv_q2_kernel<<<(Cc + 7) / 8, 256, 0, stream>>>(q1b, q_w2, q_b2, q2b, Cc);
        conv_k2_kernel<<<Cc, 256, 0, stream>>>(k1b, k_w2, k_b2, k2b);
        att_kernel<<<Cc, 64, 0, stream>>>(q2b, k2b, ab);
        gcn_inp_kernel<<<Cc, 256, 0, stream>>>(xc, ab, dctb, gib);

        const int rows = Cc * FEATN;
        const int g1 = (rows + 31) / 32;
        // gin: T = gin_att @ gi (40-wide); Y = tanh(bn(T @ gin_w + gin_b))
        attmul_gin_kernel<<<Cc, 256, 0, stream>>>(gib, gin_att, Tb);
        wmul_kernel<40, false><<<g1, 256, 0, stream>>>(Tb, gin_w, gin_b,
                                                       bn_in_g, bn_in_b, nullptr, Yb, rows);
        float* ycur = Yb;
        float* yscr = Zb;
        for (int i = 0; i < 12; i += 2) {
            attmul_kernel<<<Cc, 256, 0, stream>>>(ycur, blk_att + (size_t)i * 4356, Tb);
            wmul_kernel<256, false><<<g1, 256, 0, stream>>>(
                Tb, blk_w + (size_t)i * 65536, blk_b + (size_t)i * 256,
                blk_bn_g + (size_t)i * NNDIM, blk_bn_b + (size_t)i * NNDIM,
                nullptr, yscr, rows);
            attmul_kernel<<<Cc, 256, 0, stream>>>(yscr, blk_att + (size_t)(i + 1) * 4356, Tb);
            wmul_kernel<256, true><<<g1, 256, 0, stream>>>(
                Tb, blk_w + (size_t)(i + 1) * 65536, blk_b + (size_t)(i + 1) * 256,
                blk_bn_g + (size_t)(i + 1) * NNDIM, blk_bn_b + (size_t)(i + 1) * NNDIM,
                ycur /* residual */, yscr, rows);
            float* t = ycur; ycur = yscr; yscr = t;
        }
        // gout + idct
        attmul_kernel<<<Cc, 256, 0, stream>>>(ycur, gout_att, Tb);
        final_kernel<<<Cc, 256, 0, stream>>>(Tb, gout_w, gout_b, gib, dctb, outc);
    }
}

// Round 8
// 9044.497 us; speedup vs baseline: 4.9104x; 1.1717x over previous
//
#include <hip/hip_runtime.h>
#include <math.h>

typedef unsigned short u16;
typedef unsigned int u32;

#define FEATN 66
#define HIDN 256
#define NNDIM 16896      // 66*256
#define INVS 0.9999950000374998f
#ifndef M_PI
#define M_PI 3.14159265358979323846
#endif

typedef __attribute__((ext_vector_type(4))) float f32x4;
typedef __attribute__((ext_vector_type(8))) short s16x8;

__device__ __forceinline__ u32 bf_rne(float x) {
    u32 i = __float_as_uint(x);
    return (i + 0x7fffu + ((i >> 16) & 1u)) >> 16;
}

// ---------------- DCT matrix (parallel build; orthonormal: inv = transpose) ----------------
__global__ void dct_kernel(float* __restrict__ dct) {
    int t = threadIdx.x;
    if (t < 400) {
        int k = t / 20, i = t % 20;
        double w = (k == 0) ? sqrt(1.0 / 20.0) : sqrt(2.0 / 20.0);
        dct[t] = (float)(w * cos(M_PI * (i + 0.5) * k / 20.0));
    }
}

// ---------------- pack blk_w into split-bf16 MFMA B-fragment layout ----------------
// index within layer: (ks*16 + ct)*512 + lane*8 + j ; value = W[k=ks*32+(lane>>4)*8+j][n=ct*16+(lane&15)]
__global__ __launch_bounds__(256) void pack_w_kernel(
    const float* __restrict__ blk_w, u16* __restrict__ wh, u16* __restrict__ wl) {
    int gid = blockIdx.x * 256 + threadIdx.x;
    if (gid >= 12 * 65536) return;
    int layer = gid >> 16, rmd = gid & 65535;
    int ks = rmd >> 13;
    int r2 = rmd & 8191;
    int ct = r2 >> 9;
    int r3 = r2 & 511;
    int lane = r3 >> 3, j = r3 & 7;
    int k = ks * 32 + (lane >> 4) * 8 + j;
    int n = ct * 16 + (lane & 15);
    float v = blk_w[(size_t)layer * 65536 + k * 256 + n];
    u32 rhi = bf_rne(v);
    float hif = __uint_as_float(rhi << 16);
    u32 rlo = bf_rne(v - hif);
    wh[gid] = (u16)rhi;
    wl[gid] = (u16)rlo;
}

// ---------------- conv q1: x[b,40:50,:] -> q1[b,c,p] p<5 ----------------
__global__ __launch_bounds__(256) void conv_q1_kernel(
    const float* __restrict__ x, const float* __restrict__ w1,
    const float* __restrict__ b1, float* __restrict__ q1) {
    __shared__ float xs[10 * FEATN];
    const int b = blockIdx.x, tid = threadIdx.x;
    const float* xb = x + (size_t)b * 3300 + 40 * FEATN;
    for (int idx = tid; idx < 660; idx += 256) xs[idx] = xb[idx];
    __syncthreads();
    const int c = tid;
    float acc[5];
    float bv = b1[c];
#pragma unroll
    for (int p = 0; p < 5; p++) acc[p] = bv;
    const float* wc = w1 + (size_t)c * 396;
    for (int f = 0; f < FEATN; f++) {
        float xr[10];
#pragma unroll
        for (int j = 0; j < 10; j++) xr[j] = xs[j * FEATN + f];
#pragma unroll
        for (int t = 0; t < 6; t++) {
            float wv = wc[f * 6 + t];
#pragma unroll
            for (int p = 0; p < 5; p++) acc[p] = fmaf(xr[p + t], wv, acc[p]);
        }
    }
#pragma unroll
    for (int p = 0; p < 5; p++)
        q1[(size_t)b * 1280 + c * 5 + p] = fmaxf(acc[p], 0.f);
}

// ---------------- conv k1: x[b,0:40,:] -> k1[b,c,p] p<35 ----------------
__global__ __launch_bounds__(256) void conv_k1_kernel(
    const float* __restrict__ x, const float* __restrict__ w1,
    const float* __restrict__ b1, float* __restrict__ k1) {
    __shared__ float xs[40 * FEATN];
    const int b = blockIdx.x, ct = blockIdx.y, tid = threadIdx.x;
    const float* xb = x + (size_t)b * 3300;
    for (int idx = tid; idx < 2640; idx += 256) xs[idx] = xb[idx];
    __syncthreads();
    const int c = tid & 31, pg = tid >> 5;
    if (pg >= 7) return;
    const int cg = ct * 32 + c;
    float acc[5];
    float bv = b1[cg];
#pragma unroll
    for (int q = 0; q < 5; q++) acc[q] = bv;
    const float* wc = w1 + (size_t)cg * 396;
    for (int f = 0; f < FEATN; f++) {
        float xr[10];
#pragma unroll
        for (int j = 0; j < 10; j++) xr[j] = xs[(pg * 5 + j) * FEATN + f];
#pragma unroll
        for (int t = 0; t < 6; t++) {
            float wv = wc[f * 6 + t];
#pragma unroll
            for (int q = 0; q < 5; q++) acc[q] = fmaf(xr[q + t], wv, acc[q]);
        }
    }
#pragma unroll
    for (int q = 0; q < 5; q++)
        k1[(size_t)b * 8960 + cg * 35 + pg * 5 + q] = fmaxf(acc[q], 0.f);
}

// ---------------- conv q2: q1[b,:,0:5] -> q2[b,c], 8 batches/block ----------------
__global__ __launch_bounds__(256) void conv_q2_kernel(
    const float* __restrict__ q1, const float* __restrict__ w2,
    const float* __restrict__ b2, float* __restrict__ q2, int Cc) {
    __shared__ float q1s[8 * 1280];
    const int b0 = blockIdx.x * 8, tid = threadIdx.x;
    for (int idx = tid; idx < 8 * 1280; idx += 256) {
        int bb = b0 + idx / 1280;
        q1s[idx] = (bb < Cc) ? q1[(size_t)b0 * 1280 + idx] : 0.f;
    }
    __syncthreads();
    const int c = tid;
    float acc[8];
    float bv = b2[c];
#pragma unroll
    for (int bb = 0; bb < 8; bb++) acc[bb] = bv;
    const float* wc = w2 + (size_t)c * 1280;
    for (int h = 0; h < 256; h++) {
        float wv[5];
#pragma unroll
        for (int t = 0; t < 5; t++) wv[t] = wc[h * 5 + t];
#pragma unroll
        for (int bb = 0; bb < 8; bb++) {
#pragma unroll
            for (int t = 0; t < 5; t++)
                acc[bb] = fmaf(q1s[bb * 1280 + h * 5 + t], wv[t], acc[bb]);
        }
    }
#pragma unroll
    for (int bb = 0; bb < 8; bb++)
        if (b0 + bb < Cc)
            q2[(size_t)(b0 + bb) * 256 + c] = fmaxf(acc[bb], 0.f);
}

// ---------------- conv k2: k1[b,:,s:s+5] -> k2[b,c,s], s split in 2 blocks ----------------
__global__ __launch_bounds__(256) void conv_k2_kernel(
    const float* __restrict__ k1, const float* __restrict__ w2,
    const float* __restrict__ b2, float* __restrict__ k2) {
    __shared__ float k1s[256 * 35];
    const int b = blockIdx.x, by = blockIdx.y, tid = threadIdx.x;
    for (int idx = tid; idx < 8960; idx += 256)
        k1s[idx] = k1[(size_t)b * 8960 + idx];
    __syncthreads();
    const int c = tid;
    const int s0 = by * 16;
    const int ns = (31 - s0 < 16) ? (31 - s0) : 16;
    float acc[16];
    float bv = b2[c];
#pragma unroll
    for (int s = 0; s < 16; s++) acc[s] = bv;
    const float* wc = w2 + (size_t)c * 1280;
    for (int h = 0; h < 256; h++) {
        float row[20];
#pragma unroll
        for (int j = 0; j < 20; j++) row[j] = k1s[h * 35 + s0 + j];
        float wv[5];
#pragma unroll
        for (int t = 0; t < 5; t++) wv[t] = wc[h * 5 + t];
#pragma unroll
        for (int t = 0; t < 5; t++) {
#pragma unroll
            for (int s = 0; s < 16; s++)
                acc[s] = fmaf(row[s + t], wv[t], acc[s]);
        }
    }
    for (int s = 0; s < ns; s++)
        k2[(size_t)b * 7936 + c * 31 + s0 + s] = fmaxf(acc[s], 0.f);
}

// ---------------- attention weights (one wave per batch) ----------------
__global__ void att_kernel(const float* __restrict__ q2, const float* __restrict__ k2,
                           float* __restrict__ att) {
    __shared__ float q2s[256];
    const int b = blockIdx.x, tid = threadIdx.x;
    for (int i = tid; i < 256; i += 64) q2s[i] = q2[(size_t)b * 256 + i];
    __syncthreads();
    float sc = 0.f;
    if (tid < 31) {
        const float* kp = k2 + (size_t)b * 7936 + tid;
        for (int c = 0; c < 256; c++) sc = fmaf(q2s[c], kp[c * 31], sc);
    }
    float tot = sc;
#pragma unroll
    for (int off = 1; off < 64; off <<= 1) tot += __shfl_xor(tot, off);
    if (tid < 31) att[(size_t)b * 32 + tid] = (tot != 0.f) ? (sc / tot) : 0.f;
}

// ---------------- gcn_inp = concat(padded_query, att_final) ----------------
__global__ __launch_bounds__(256) void gcn_inp_kernel(
    const float* __restrict__ x, const float* __restrict__ att,
    const float* __restrict__ dct, float* __restrict__ ginp) {
    __shared__ float xs[3300];
    __shared__ float dctS[400];
    __shared__ float attS[31];
    const int b = blockIdx.x, tid = threadIdx.x;
    const float* xb = x + (size_t)b * 3300;
    for (int idx = tid; idx < 3300; idx += 256) xs[idx] = xb[idx];
    for (int idx = tid; idx < 400; idx += 256) dctS[idx] = dct[idx];
    if (tid < 31) attS[tid] = att[(size_t)b * 32 + tid];
    __syncthreads();
    for (int idx = tid; idx < 2640; idx += 256) {
        int n = idx / 40, l = idx - n * 40;
        float acc = 0.f;
        if (l < 20) {
#pragma unroll
            for (int l1 = 0; l1 < 20; l1++) {
                int r = (l1 < 10) ? (40 + l1) : 49;   // pidx
                acc = fmaf(xs[r * FEATN + n], dctS[l1 * 20 + l], acc);
            }
        } else {
            int j = l - 20;
            for (int s2 = 0; s2 < 31; s2++) {
                int m = n * 31 + s2;                   // flat-reshape semantics
                int s1 = m / 66, f1 = m - s1 * 66;
                float inner = 0.f;
#pragma unroll
                for (int l1 = 0; l1 < 20; l1++)
                    inner = fmaf(xs[(s1 + l1) * FEATN + f1], dctS[l1 * 20 + j], inner);
                acc = fmaf(attS[s2], inner, acc);
            }
        }
        ginp[(size_t)b * 2640 + idx] = acc;
    }
}

// ---------------- attmul (gin, 40-wide): T[b] = gin_att @ gi[b] ----------------
__global__ __launch_bounds__(256) void attmul_gin_kernel(
    const float* __restrict__ ginp, const float* __restrict__ attm,
    float* __restrict__ out) {
    __shared__ float gS[2640];
    __shared__ float attS[4356];
    const int b = blockIdx.x, tid = threadIdx.x;
    for (int idx = tid; idx < 2640; idx += 256) gS[idx] = ginp[(size_t)b * 2640 + idx];
    for (int idx = tid; idx < 4356; idx += 256) attS[idx] = attm[idx];
    __syncthreads();
    for (int idx = tid; idx < 2640; idx += 256) {
        int n = idx / 40, l = idx - n * 40;
        float acc = 0.f;
        for (int m = 0; m < 66; m++)
            acc = fmaf(attS[n * 66 + m], gS[m * 40 + l], acc);
        out[(size_t)b * 2640 + idx] = acc;
    }
}

// ---------------- attmul (256-wide): out[b] = attm @ S[b], column-tiled, in-place safe ----------------
__global__ __launch_bounds__(256) void attmul_kernel(
    const float* __restrict__ S, const float* __restrict__ attm,
    float* __restrict__ out) {
    __shared__ float Ss[66 * 64];
    __shared__ float attS[4356];
    const int b = blockIdx.x, tid = threadIdx.x;
    for (int idx = tid; idx < 4356; idx += 256) attS[idx] = attm[idx];
    const float* Sb = S + (size_t)b * NNDIM;
    float* ob = out + (size_t)b * NNDIM;
    const int fl = tid & 63, ng = tid >> 6;
    for (int f0 = 0; f0 < 256; f0 += 64) {
        __syncthreads();
        for (int idx = tid; idx < 66 * 64; idx += 256) {
            int m = idx >> 6, j = idx & 63;
            Ss[idx] = Sb[m * 256 + f0 + j];
        }
        __syncthreads();
        for (int n = ng; n < 66; n += 4) {
            float acc = 0.f;
            const float* ar = &attS[n * 66];
#pragma unroll 11
            for (int m = 0; m < 66; m++)
                acc = fmaf(ar[m], Ss[(m << 6) + fl], acc);
            ob[n * 256 + f0 + fl] = acc;
        }
    }
}

// ---------------- wmul f32 (K=40 gin layer only) ----------------
template <int K, bool RES>
__global__ __launch_bounds__(256) void wmul_kernel(
    const float* __restrict__ Z, const float* __restrict__ W,
    const float* __restrict__ bias, const float* __restrict__ g,
    const float* __restrict__ beta, const float* __restrict__ res,
    float* __restrict__ out, int rows) {
    __shared__ float As[32 * K];
    const int tid = threadIdx.x;
    const size_t row0 = (size_t)blockIdx.x * 32;
    for (int idx = tid; idx < 32 * K; idx += 256) {
        int r = (int)row0 + idx / K;
        As[idx] = (r < rows) ? Z[row0 * K + idx] : 0.f;
    }
    __syncthreads();
    const int fq = tid & 63, rg = tid >> 6;
    float acc[8][4];
#pragma unroll
    for (int r = 0; r < 8; r++)
#pragma unroll
        for (int c = 0; c < 4; c++) acc[r][c] = 0.f;
    for (int i = 0; i < K; i += 4) {
        float w0[4], w1[4], w2[4], w3[4];
#pragma unroll
        for (int fi = 0; fi < 4; fi++) {
            w0[fi] = W[(size_t)(i + 0) * HIDN + fi * 64 + fq];
            w1[fi] = W[(size_t)(i + 1) * HIDN + fi * 64 + fq];
            w2[fi] = W[(size_t)(i + 2) * HIDN + fi * 64 + fq];
            w3[fi] = W[(size_t)(i + 3) * HIDN + fi * 64 + fq];
        }
#pragma unroll
        for (int rr = 0; rr < 8; rr++) {
            const float4 a = *(const float4*)&As[(rg * 8 + rr) * K + i];
#pragma unroll
            for (int fi = 0; fi < 4; fi++) {
                acc[rr][fi] = fmaf(a.x, w0[fi], acc[rr][fi]);
                acc[rr][fi] = fmaf(a.y, w1[fi], acc[rr][fi]);
                acc[rr][fi] = fmaf(a.z, w2[fi], acc[rr][fi]);
                acc[rr][fi] = fmaf(a.w, w3[fi], acc[rr][fi]);
            }
        }
    }
#pragma unroll
    for (int rr = 0; rr < 8; rr++) {
        int r = (int)row0 + rg * 8 + rr;
        if (r >= rows) continue;
        int n = r % 66;
#pragma unroll
        for (int fi = 0; fi < 4; fi++) {
            int f = fi * 64 + fq;
            float v = (acc[rr][fi] + bias[f]) * INVS;
            v = tanhf(fmaf(v, g[n * 256 + f], beta[n * 256 + f]));
            if (RES) v += res[(size_t)r * 256 + f];
            out[(size_t)r * 256 + f] = v;
        }
    }
}

// ---------------- wmul MFMA split-bf16: out = tanh(bn(Z@W+bias)) [+res]; in-place safe ----------------
template <bool RES>
__global__ __launch_bounds__(256) void wmul_mfma_kernel(
    const float* __restrict__ Z, const u16* __restrict__ wh,
    const u16* __restrict__ wl, const float* __restrict__ bias,
    const float* __restrict__ g, const float* __restrict__ beta,
    const float* __restrict__ res, float* __restrict__ out, int rows) {
    __shared__ u16 Ah[64 * 136];   // 17.4 KB, stride 136 u16 = 272 B (16B-aligned rows)
    __shared__ u16 Al[64 * 136];
    const int tid = threadIdx.x;
    const int lane = tid & 63, wid = tid >> 6;
    const int m = lane & 15, quad = lane >> 4;
    const int row0 = blockIdx.x * 64;
    f32x4 acc[4][4];
#pragma unroll
    for (int rt = 0; rt < 4; rt++)
#pragma unroll
        for (int ct = 0; ct < 4; ct++) acc[rt][ct] = (f32x4)0.f;

    for (int ph = 0; ph < 2; ph++) {
        __syncthreads();
        for (int idx = tid; idx < 64 * 128; idx += 256) {
            int r = idx >> 7, kk = idx & 127;
            int grow = row0 + r;
            float a = (grow < rows) ? Z[(size_t)grow * 256 + ph * 128 + kk] : 0.f;
            u32 rhi = bf_rne(a);
            float hif = __uint_as_float(rhi << 16);
            u32 rlo = bf_rne(a - hif);
            Ah[r * 136 + kk] = (u16)rhi;
            Al[r * 136 + kk] = (u16)rlo;
        }
        __syncthreads();
#pragma unroll
        for (int ks = 0; ks < 4; ks++) {
            const int ksg = ph * 4 + ks;
            s16x8 ahf[4], alf[4], bhf[4], blf[4];
#pragma unroll
            for (int rt = 0; rt < 4; rt++) {
                int off = (rt * 16 + m) * 136 + ks * 32 + quad * 8;
                ahf[rt] = *(const s16x8*)&Ah[off];
                alf[rt] = *(const s16x8*)&Al[off];
            }
#pragma unroll
            for (int ct = 0; ct < 4; ct++) {
                size_t boff = ((size_t)(ksg * 16 + wid * 4 + ct)) * 512 + lane * 8;
                bhf[ct] = *(const s16x8*)&wh[boff];
                blf[ct] = *(const s16x8*)&wl[boff];
            }
#pragma unroll
            for (int rt = 0; rt < 4; rt++) {
#pragma unroll
                for (int ct = 0; ct < 4; ct++) {
                    acc[rt][ct] = __builtin_amdgcn_mfma_f32_16x16x32_bf16(
                        ahf[rt], bhf[ct], acc[rt][ct], 0, 0, 0);
                    acc[rt][ct] = __builtin_amdgcn_mfma_f32_16x16x32_bf16(
                        ahf[rt], blf[ct], acc[rt][ct], 0, 0, 0);
                    acc[rt][ct] = __builtin_amdgcn_mfma_f32_16x16x32_bf16(
                        alf[rt], bhf[ct], acc[rt][ct], 0, 0, 0);
                }
            }
        }
    }
#pragma unroll
    for (int rt = 0; rt < 4; rt++) {
        int rbase = row0 + rt * 16 + quad * 4;
#pragma unroll
        for (int r = 0; r < 4; r++) {
            int grow = rbase + r;
            if (grow >= rows) continue;
            int n = grow % 66;
#pragma unroll
            for (int ct = 0; ct < 4; ct++) {
                int f = wid * 64 + ct * 16 + m;
                float v = (acc[rt][ct][r] + bias[f]) * INVS;
                v = tanhf(fmaf(v, g[n * 256 + f], beta[n * 256 + f]));
                if (RES) v += res[(size_t)grow * 256 + f];
                out[(size_t)grow * 256 + f] = v;
            }
        }
    }
}

// ---------------- final: go = (T@gw)[:, :20] + gb + gi[:, :20]; out = go @ dct^T ----------------
__global__ __launch_bounds__(256) void final_kernel(
    const float* __restrict__ T, const float* __restrict__ gw,
    const float* __restrict__ gb, const float* __restrict__ gi,
    const float* __restrict__ dct, float* __restrict__ out) {
    __shared__ float Zt[66 * 64];
    __shared__ float gwS[256 * 20];
    __shared__ float goS[1320];
    __shared__ float dctS[400];
    const int b = blockIdx.x, tid = threadIdx.x;
    for (int idx = tid; idx < 5120; idx += 256) {
        int i = idx / 20, l = idx - i * 20;
        gwS[idx] = gw[i * 40 + l];
    }
    for (int idx = tid; idx < 400; idx += 256) dctS[idx] = dct[idx];
    for (int idx = tid; idx < 1320; idx += 256) {
        int n = idx / 20, l = idx - n * 20;
        goS[idx] = gb[l] + gi[(size_t)b * 2640 + n * 40 + l];
    }
    for (int t = 0; t < 4; t++) {
        __syncthreads();
        for (int idx = tid; idx < 66 * 64; idx += 256) {
            int mm = idx >> 6, j = idx & 63;
            Zt[idx] = T[(size_t)b * NNDIM + mm * 256 + t * 64 + j];
        }
        __syncthreads();
        for (int idx = tid; idx < 1320; idx += 256) {
            int n = idx / 20, l = idx - n * 20;
            float acc = 0.f;
#pragma unroll
            for (int j = 0; j < 64; j++)
                acc = fmaf(Zt[(n << 6) + j], gwS[(t * 64 + j) * 20 + l], acc);
            goS[idx] += acc;
        }
    }
    __syncthreads();
    for (int idx = tid; idx < 1320; idx += 256) {
        int n = idx / 20, mm = idx - n * 20;
        float o = 0.f;
#pragma unroll
        for (int l = 0; l < 20; l++)
            o = fmaf(goS[n * 20 + l], dctS[mm * 20 + l], o);   // idct = dct^T
        out[(size_t)b * 1320 + idx] = o;
    }
}

extern "C" void kernel_launch(void* const* d_in, const int* in_sizes, int n_in,
                              void* d_out, int out_size, void* d_ws, size_t ws_size,
                              hipStream_t stream) {
    const float* x        = (const float*)d_in[0];
    const float* q_w1     = (const float*)d_in[1];
    const float* q_b1     = (const float*)d_in[2];
    const float* q_w2     = (const float*)d_in[3];
    const float* q_b2     = (const float*)d_in[4];
    const float* k_w1     = (const float*)d_in[5];
    const float* k_b1     = (const float*)d_in[6];
    const float* k_w2     = (const float*)d_in[7];
    const float* k_b2     = (const float*)d_in[8];
    const float* gin_w    = (const float*)d_in[9];
    const float* gin_att  = (const float*)d_in[10];
    const float* gin_b    = (const float*)d_in[11];
    const float* bn_in_g  = (const float*)d_in[12];
    const float* bn_in_b  = (const float*)d_in[13];
    const float* blk_w    = (const float*)d_in[14];
    const float* blk_att  = (const float*)d_in[15];
    const float* blk_b    = (const float*)d_in[16];
    const float* blk_bn_g = (const float*)d_in[17];
    const float* blk_bn_b = (const float*)d_in[18];
    const float* gout_w   = (const float*)d_in[19];
    const float* gout_att = (const float*)d_in[20];
    const float* gout_b   = (const float*)d_in[21];
    float* out = (float*)d_out;

    const int B = in_sizes[0] / 3300;

    // Layout: dct (400 f) | packed split-bf16 weights (2 x 786432 u16 = 3 MB) | chunk region
    float* dctb = (float*)d_ws;
    u16* wpk_hi = (u16*)((char*)d_ws + 4096);
    u16* wpk_lo = wpk_hi + 12 * 65536;
    const size_t BASE = 4096 + (size_t)2 * 12 * 65536 * 2;   // 3,149,824
    char* R = (char*)d_ws + BASE;
    size_t avail = (ws_size > BASE) ? (ws_size - BASE) : 0;

    // Per-batch floats: Y 16896 + T 16896 + gi 2640 + att 32 + q2 256 = 36720
    const size_t PER_B = 36720ull * 4ull;   // 146,880 B
    int C = B;
    while (C > 1 && (size_t)C * PER_B > avail) C >>= 1;

    dct_kernel<<<1, 512, 0, stream>>>(dctb);
    pack_w_kernel<<<(12 * 65536) / 256, 256, 0, stream>>>(blk_w, wpk_hi, wpk_lo);

    for (int c0 = 0; c0 < B; c0 += C) {
        const int Cc = (B - c0 < C) ? (B - c0) : C;
        const float* xc = x + (size_t)c0 * 3300;
        float* outc = out + (size_t)c0 * 1320;

        float* Yb  = (float*)R;                      // C*16896
        float* Tb  = Yb + (size_t)C * 16896;         // C*16896
        float* gib = Tb + (size_t)C * 16896;         // C*2640
        float* ab  = gib + (size_t)C * 2640;         // C*32
        float* q2b = ab + (size_t)C * 32;            // C*256
        // conv temporaries aliased into dead zones:
        float* k1b = Yb;                             // C*8960  (dead after conv_k2)
        float* k2b = Tb;                             // C*7936  (dead after att)
        float* q1b = gib;                            // C*1280  (dead before gi written)

        conv_q1_kernel<<<Cc, 256, 0, stream>>>(xc, q_w1, q_b1, q1b);
        conv_k1_kernel<<<dim3(Cc, 8), 256, 0, stream>>>(xc, k_w1, k_b1, k1b);
        conv_q2_kernel<<<(Cc + 7) / 8, 256, 0, stream>>>(q1b, q_w2, q_b2, q2b, Cc);
        conv_k2_kernel<<<dim3(Cc, 2), 256, 0, stream>>>(k1b, k_w2, k_b2, k2b);
        att_kernel<<<Cc, 64, 0, stream>>>(q2b, k2b, ab);
        gcn_inp_kernel<<<Cc, 256, 0, stream>>>(xc, ab, dctb, gib);

        const int rows = Cc * FEATN;
        const int g32 = (rows + 31) / 32;
        const int g64 = (rows + 63) / 64;

        // gin: T = gin_att @ gi (40-wide, flat); Y = tanh(bn(T @ gin_w + gin_b))
        attmul_gin_kernel<<<Cc, 256, 0, stream>>>(gib, gin_att, Tb);
        wmul_kernel<40, false><<<g32, 256, 0, stream>>>(Tb, gin_w, gin_b,
                                                        bn_in_g, bn_in_b, nullptr, Yb, rows);
        // 6 residual pairs: Y -> T -> T -> T -> Y(+res)
        for (int i = 0; i < 12; i += 2) {
            attmul_kernel<<<Cc, 256, 0, stream>>>(Yb, blk_att + (size_t)i * 4356, Tb);
            wmul_mfma_kernel<false><<<g64, 256, 0, stream>>>(
                Tb, wpk_hi + (size_t)i * 65536, wpk_lo + (size_t)i * 65536,
                blk_b + (size_t)i * 256,
                blk_bn_g + (size_t)i * NNDIM, blk_bn_b + (size_t)i * NNDIM,
                nullptr, Tb, rows);
            attmul_kernel<<<Cc, 256, 0, stream>>>(Tb, blk_att + (size_t)(i + 1) * 4356, Tb);
            wmul_mfma_kernel<true><<<g64, 256, 0, stream>>>(
                Tb, wpk_hi + (size_t)(i + 1) * 65536, wpk_lo + (size_t)(i + 1) * 65536,
                blk_b + (size_t)(i + 1) * 256,
                blk_bn_g + (size_t)(i + 1) * NNDIM, blk_bn_b + (size_t)(i + 1) * NNDIM,
                Yb /* residual */, Yb, rows);
        }
        // gout + idct
        attmul_kernel<<<Cc, 256, 0, stream>>>(Yb, gout_att, Tb);
        final_kernel<<<Cc, 256, 0, stream>>>(Tb, gout_w, gout_b, gib, dctb, outc);
    }
}